// Round 12
// baseline (705.000 us; speedup 1.0000x reference)
//
#include <hip/hip_runtime.h>
#include <math.h>

// Problem constants
#define DM    512
#define DI    1024
#define DSN   16
#define DTR   32
#define DFFN  2048
#define BB    8
#define SS    512
#define TTM   1024
#define LCAT  1536
#define NC    32      // scan chunks per sequence

#define ACT_NONE     0
#define ACT_RELU     1
#define ACT_DELTA    3   // n<1024: softplus+bias -> Cb(delta bf16); n-tile 8 -> C2(bc fp32)

typedef __attribute__((ext_vector_type(8))) short short8;
typedef __attribute__((ext_vector_type(8))) unsigned short ushort8;
typedef __attribute__((ext_vector_type(4))) float f32x4;

__device__ __forceinline__ unsigned short f2b(float f) {
    unsigned int u = __float_as_uint(f);
    return (unsigned short)((u + 0x7FFFu + ((u >> 16) & 1u)) >> 16);
}
__device__ __forceinline__ float b2f(unsigned short h) {
    return __uint_as_float(((unsigned int)h) << 16);
}
__device__ __forceinline__ float fast_softplus(float v) {
    return (v > 20.f) ? v : __logf(1.f + __expf(v));
}
__device__ __forceinline__ void gld16(const void* g, void* l) {
    __builtin_amdgcn_global_load_lds(
        (const __attribute__((address_space(1))) void*)g,
        (__attribute__((address_space(3))) void*)l, 16, 0, 0);
}

__device__ __forceinline__ int map_row(int m, int mb, int bs, int ro) {
    int q = m / mb;
    return q * bs + ro + (m - q * mb);
}

// ================= bf16 MFMA GEMM: C[m,n] = act(A[row(m),k] * W[n,k] + bias[n])
// Tile 128x128, BK=64. K-loop LDS swizzle: 2-bit quad XOR (R10's — fastest
// staging; R11's 3-bit variant regressed in-proj 59->82 by swapping 64B
// half-rows and breaking cross-quad merges): chunk (r, g in 0..7) at
// p = r*8 + (g&4) + ((g&3) ^ (r&3)). Accept 4-way read conflicts (+4cyc/b128).
// Epilogue (bf16 outs): LDS-transpose — K-loop LDS (32KB) == one 128x128 bf16
// tile; acc written in with per-row chunk phase XOR, then 8x ushort8 coalesced
// stores per thread (replaces 64 scalar 2B stores).
// Split-K via gridDim.z==2 (fp32 out path): z=1 writes partials to Cf2, no bias.
__global__ __launch_bounds__(256) void mgemm_kernel(
    const unsigned short* __restrict__ A, int mb, int bs, int ro,
    const unsigned short* __restrict__ W, const float* __restrict__ bias,
    float* __restrict__ Cf, unsigned short* __restrict__ Cb,
    float* __restrict__ C2, float* __restrict__ Cf2,
    int N, int K, int act)
{
    __shared__ __align__(16) unsigned short Sm[16384];   // 32 KB
    unsigned short* As = Sm;
    unsigned short* Bs = Sm + 8192;
    int tid = threadIdx.x;
    int lane = tid & 63, wave = tid >> 6;
    int wy = wave >> 1, wx = wave & 1;
    // XCD-band swizzle over (x,y); z (split-K) reuses the same mapping
    int nx = gridDim.x;
    int f = blockIdx.y * nx + blockIdx.x;
    int xcd = f & 7, j2 = f >> 3;
    int bandh = gridDim.y >> 3;
    int m0 = (xcd * bandh + j2 / nx) * 128;
    int n0 = (j2 % nx) * 128;
    // split-K
    int Kh = K / gridDim.z;
    int kbeg = blockIdx.z * Kh, kend = kbeg + Kh;
    float* Cfo = Cf;
    const float* biaso = bias;
    if (blockIdx.z) { Cfo = Cf2; biaso = nullptr; }

    // staging: wave stages chunk positions c = wave*256 + j*64 + lane (j=0..3)
    const unsigned short* ga[4];
    const unsigned short* gb[4];
    unsigned short* la[4];
    unsigned short* lb[4];
    #pragma unroll
    for (int j = 0; j < 4; j++) {
        int c  = wave * 256 + j * 64 + lane;
        int r  = c >> 3;                    // tile row 0..127
        int q  = c & 7;
        int g  = (q & 4) | ((q & 3) ^ (r & 3));   // un-swizzled k-chunk 0..7
        int arow = map_row(m0 + r, mb, bs, ro);
        ga[j] = A + (size_t)arow * K + g * 8;
        gb[j] = W + (size_t)(n0 + r) * K + g * 8;
        la[j] = As + (size_t)(wave * 256 + j * 64) * 8;   // chunk pos * 8 shorts
        lb[j] = Bs + (size_t)(wave * 256 + j * 64) * 8;
    }
    // fragment read bases; R&3 == fm&3 (wy*64, t*16 are mult of 4)
    int fm = lane & 15, fg = lane >> 4;
    int sw = fg ^ (fm & 3);
    const unsigned short* arp = As + ((size_t)(wy * 64 + fm) * 8 + sw) * 8;
    const unsigned short* brp = Bs + ((size_t)(wx * 64 + fm) * 8 + sw) * 8;

    f32x4 acc[4][4];
    #pragma unroll
    for (int i = 0; i < 4; i++)
        #pragma unroll
        for (int j = 0; j < 4; j++) acc[i][j] = 0.f;

    for (int k0 = kbeg; k0 < kend; k0 += 64) {
        #pragma unroll
        for (int j = 0; j < 4; j++) {
            gld16(ga[j] + k0, la[j]);
            gld16(gb[j] + k0, lb[j]);
        }
        __syncthreads();
        #pragma unroll
        for (int h = 0; h < 2; h++) {
            short8 af[4], bfr[4];
            #pragma unroll
            for (int t = 0; t < 4; t++) af[t]  = *(const short8*)(arp + h * 32 + t * 1024);
            #pragma unroll
            for (int t = 0; t < 4; t++) bfr[t] = *(const short8*)(brp + h * 32 + t * 1024);
            #pragma unroll
            for (int i = 0; i < 4; i++)
                #pragma unroll
                for (int j = 0; j < 4; j++)
                    acc[i][j] = __builtin_amdgcn_mfma_f32_16x16x32_bf16(af[i], bfr[j], acc[i][j], 0, 0, 0);
        }
        __syncthreads();
    }

    // epilogue: C/D layout col=lane&15 (n), row=(lane>>4)*4+reg (m)
    int en = lane & 15, em = (lane >> 4) * 4;
    if (act == ACT_DELTA && n0 >= 1024) {
        // bc tile: cols 1024..1055 -> fp32 scalar
        #pragma unroll
        for (int j = 0; j < 4; j++) {
            int n = n0 + wx * 64 + j * 16 + en;
            if (n >= 1056) continue;
            #pragma unroll
            for (int i = 0; i < 4; i++) {
                int mbase = m0 + wy * 64 + i * 16 + em;
                #pragma unroll
                for (int r = 0; r < 4; r++)
                    C2[(size_t)(mbase + r) * 32 + (n - 1024)] = acc[i][j][r];
            }
        }
        return;
    }
    if (Cb) {
        // LDS-transpose vectorized bf16 store (K-loop LDS is free post-barrier)
        #pragma unroll
        for (int j = 0; j < 4; j++) {
            int C = wx * 64 + j * 16 + en;
            float bv = bias ? bias[n0 + C] : 0.f;
            #pragma unroll
            for (int i = 0; i < 4; i++) {
                int R0 = wy * 64 + i * 16 + em;
                #pragma unroll
                for (int r = 0; r < 4; r++) {
                    float v = acc[i][j][r] + bv;
                    if (act == ACT_RELU) v = v > 0.f ? v : 0.f;
                    else if (act == ACT_DELTA) v = fast_softplus(v);
                    int R = R0 + r;
                    Sm[R * 128 + (((C >> 3) ^ (R & 7)) << 3) + (C & 7)] = f2b(v);
                }
            }
        }
        __syncthreads();
        int row = tid & 127, half = tid >> 7;
        int strideB = (act == ACT_DELTA) ? 1024 : N;
        unsigned short* gp = Cb + (size_t)(m0 + row) * strideB + n0;
        const unsigned short* lp = Sm + row * 128;
        #pragma unroll
        for (int u = 0; u < 8; u++) {
            int c = half * 8 + u;
            int p = c ^ (row & 7);
            *(ushort8*)(gp + c * 8) = *(const ushort8*)(lp + p * 8);
        }
        return;
    }
    // fp32 path (with split-K partials)
    #pragma unroll
    for (int j = 0; j < 4; j++) {
        int n = n0 + wx * 64 + j * 16 + en;
        float bv = biaso ? biaso[n] : 0.f;
        #pragma unroll
        for (int i = 0; i < 4; i++) {
            int mbase = m0 + wy * 64 + i * 16 + em;
            #pragma unroll
            for (int r = 0; r < 4; r++) {
                float v = acc[i][j][r] + bv;
                Cfo[(size_t)(mbase + r) * N + n] = v;
            }
        }
    }
}

// ================= Wcomb fill: rows 0..1023 = dt_w @ xproj[:32]; 1024..1055 = xproj rows 32..63; rest 0
__global__ void wcomb_kernel(const float* __restrict__ dt_w,
                             const float* __restrict__ xproj,
                             unsigned short* __restrict__ out)
{
    int idx = blockIdx.x * 256 + threadIdx.x;   // n*1024 + k, n < 1152
    int n = idx >> 10, k = idx & 1023;
    float v = 0.f;
    if (n < 1024) {
        #pragma unroll
        for (int r = 0; r < DTR; r++)
            v = fmaf(dt_w[n * DTR + r], xproj[r * 1024 + k], v);
    } else if (n < 1056) {
        v = xproj[(n - 1024 + 32) * 1024 + k];
    }
    out[idx] = f2b(v);
}

// ================= Depthwise causal conv (width 4) + bias + SiLU, ushort8-vectorized
__global__ __launch_bounds__(256) void conv_silu_kernel(
    const unsigned short* __restrict__ xz,
    const float* __restrict__ cw,
    const float* __restrict__ cb,
    unsigned short* __restrict__ xc, int L, int total8)
{
    int idx = blockIdx.x * blockDim.x + threadIdx.x;
    if (idx >= total8) return;
    int d8 = idx & 127;
    int d0 = d8 * 8;
    int r  = idx >> 7;             // b*L + l
    int l  = r % L;
    float acc[8];
    {
        float4 c0 = ((const float4*)(cb + d0))[0];
        float4 c1 = ((const float4*)(cb + d0))[1];
        acc[0]=c0.x; acc[1]=c0.y; acc[2]=c0.z; acc[3]=c0.w;
        acc[4]=c1.x; acc[5]=c1.y; acc[6]=c1.z; acc[7]=c1.w;
    }
    float4 wv[8];
    #pragma unroll
    for (int j = 0; j < 8; j++) wv[j] = *(const float4*)(cw + (d0 + j) * 4);
    #pragma unroll
    for (int k = 0; k < 4; k++) {
        int ls = l - 3 + k;
        if (ls >= 0) {
            ushort8 v = *(const ushort8*)(xz + (size_t)(r - 3 + k) * 2048 + d0);
            const float* w = (const float*)&wv[0];
            #pragma unroll
            for (int j = 0; j < 8; j++)
                acc[j] = fmaf(b2f(v[j]), w[j * 4 + k], acc[j]);
        }
    }
    ushort8 o;
    #pragma unroll
    for (int j = 0; j < 8; j++) {
        float s = acc[j] / (1.f + __expf(-acc[j]));
        o[j] = f2b(s);
    }
    *(ushort8*)(xc + (size_t)r * 1024 + d0) = o;
}

// ================= Chunked selective scan (delta bf16)
__global__ __launch_bounds__(256) void scan_part1(
    const unsigned short* __restrict__ delta, const unsigned short* __restrict__ xc,
    const float* __restrict__ bc, const float* __restrict__ A_log,
    float* __restrict__ part_h, float* __restrict__ part_s, int L, int CH)
{
    int tid = threadIdx.x;
    int dblk = blockIdx.x & 3;
    int c    = (blockIdx.x >> 2) & (NC - 1);
    int b    = blockIdx.x >> 7;
    int d    = dblk * 256 + tid;
    float A[DSN];
    #pragma unroll
    for (int s = 0; s < DSN; s++) A[s] = -__expf(A_log[d * DSN + s]);
    float h[DSN];
    #pragma unroll
    for (int s = 0; s < DSN; s++) h[s] = 0.f;
    float ssum = 0.f;
    int l0 = c * CH;
    for (int l = l0; l < l0 + CH; l++) {
        size_t r = (size_t)b * L + l;
        float4 bq[4];
        const float4* bp = (const float4*)(bc + r * 32);
        #pragma unroll
        for (int q = 0; q < 4; q++) bq[q] = bp[q];
        const float* Bm = (const float*)&bq[0];
        float dl = b2f(delta[r * DI + d]);
        float u  = b2f(xc[r * DI + d]);
        float du = dl * u;
        ssum += dl;
        #pragma unroll
        for (int s = 0; s < DSN; s++)
            h[s] = fmaf(__expf(dl * A[s]), h[s], du * Bm[s]);
    }
    size_t base = ((size_t)(b * NC + c) * DI + d) * DSN;
    #pragma unroll
    for (int q = 0; q < 4; q++)
        ((float4*)(part_h + base))[q] = make_float4(h[q*4], h[q*4+1], h[q*4+2], h[q*4+3]);
    part_s[(size_t)(b * NC + c) * DI + d] = ssum;
}

__global__ __launch_bounds__(256) void scan_combine(
    const float* __restrict__ A_log,
    float* __restrict__ part_h, const float* __restrict__ part_s)
{
    int idx = blockIdx.x * 256 + threadIdx.x;
    int b = idx >> 10, d = idx & (DI - 1);
    float A[DSN];
    #pragma unroll
    for (int s = 0; s < DSN; s++) A[s] = -__expf(A_log[d * DSN + s]);
    float h[DSN];
    #pragma unroll
    for (int s = 0; s < DSN; s++) h[s] = 0.f;
    for (int c = 0; c < NC; c++) {
        size_t base = ((size_t)(b * NC + c) * DI + d) * DSN;
        float4 ph4[4];
        #pragma unroll
        for (int q = 0; q < 4; q++) ph4[q] = ((const float4*)(part_h + base))[q];
        const float* ph = (const float*)&ph4[0];
        float S = part_s[(size_t)(b * NC + c) * DI + d];
        #pragma unroll
        for (int q = 0; q < 4; q++)
            ((float4*)(part_h + base))[q] = make_float4(h[q*4], h[q*4+1], h[q*4+2], h[q*4+3]);
        #pragma unroll
        for (int s = 0; s < DSN; s++)
            h[s] = fmaf(__expf(A[s] * S), h[s], ph[s]);
    }
}

__global__ __launch_bounds__(256) void scan_part2(
    const unsigned short* __restrict__ delta, const unsigned short* __restrict__ xc,
    const float* __restrict__ bc, const unsigned short* __restrict__ xz,
    const float* __restrict__ A_log, const float* __restrict__ Dv,
    const float* __restrict__ part_h,
    unsigned short* __restrict__ out, int L, int CH)
{
    int tid = threadIdx.x;
    int dblk = blockIdx.x & 3;
    int c    = (blockIdx.x >> 2) & (NC - 1);
    int b    = blockIdx.x >> 7;
    int d    = dblk * 256 + tid;
    float A[DSN];
    #pragma unroll
    for (int s = 0; s < DSN; s++) A[s] = -__expf(A_log[d * DSN + s]);
    float Dvd = Dv[d];
    size_t base = ((size_t)(b * NC + c) * DI + d) * DSN;
    float h4[4][4];
    #pragma unroll
    for (int q = 0; q < 4; q++) *((float4*)h4[q]) = ((const float4*)(part_h + base))[q];
    float h[DSN];
    #pragma unroll
    for (int s = 0; s < DSN; s++) h[s] = h4[s >> 2][s & 3];
    int l0 = c * CH;
    for (int l = l0; l < l0 + CH; l++) {
        size_t r = (size_t)b * L + l;
        float4 bq[8];
        const float4* bp = (const float4*)(bc + r * 32);
        #pragma unroll
        for (int q = 0; q < 8; q++) bq[q] = bp[q];
        const float* Bm = (const float*)&bq[0];
        const float* Cm = Bm + DSN;
        float dl = b2f(delta[r * DI + d]);
        float u  = b2f(xc[r * DI + d]);
        float du = dl * u;
        float y = 0.f;
        #pragma unroll
        for (int s = 0; s < DSN; s++) {
            h[s] = fmaf(__expf(dl * A[s]), h[s], du * Bm[s]);
            y = fmaf(h[s], Cm[s], y);
        }
        float z = b2f(xz[r * 2048 + DI + d]);
        float sil = z / (1.f + __expf(-z));
        out[r * DI + d] = f2b((y + u * Dvd) * sil);
    }
}

// ================= residual add + LayerNorm; a + bsrc (+ bsrc2); fp32/bf16 outs
__global__ __launch_bounds__(128) void addln_kernel(
    const float* __restrict__ a, int amb, int absd, int aro, int lda,
    const float* __restrict__ bsrc, const float* __restrict__ bsrc2,
    const float* __restrict__ g, const float* __restrict__ be,
    float* __restrict__ outf, int omb, int obsd, int oro, int ldo,
    unsigned short* __restrict__ outb, int bmb, int bbsd, int bro, int ldb)
{
    int m = blockIdx.x, t = threadIdx.x;
    int ar = map_row(m, amb, absd, aro);
    float4 x4 = ((const float4*)(a + (size_t)ar * lda))[t];
    float4 y4 = ((const float4*)(bsrc + (size_t)m * DM))[t];
    float v[4] = {x4.x + y4.x, x4.y + y4.y, x4.z + y4.z, x4.w + y4.w};
    if (bsrc2) {
        float4 z4 = ((const float4*)(bsrc2 + (size_t)m * DM))[t];
        v[0] += z4.x; v[1] += z4.y; v[2] += z4.z; v[3] += z4.w;
    }
    float sum = v[0] + v[1] + v[2] + v[3];
    float sq  = v[0]*v[0] + v[1]*v[1] + v[2]*v[2] + v[3]*v[3];
    #pragma unroll
    for (int o = 32; o > 0; o >>= 1) {
        sum += __shfl_down(sum, o);
        sq  += __shfl_down(sq, o);
    }
    __shared__ float s0[2], s1[2];
    if ((t & 63) == 0) { s0[t >> 6] = sum; s1[t >> 6] = sq; }
    __syncthreads();
    float tot = s0[0] + s0[1];
    float tsq = s1[0] + s1[1];
    float mu = tot * (1.f / DM);
    float var = tsq * (1.f / DM) - mu * mu;
    float rs = rsqrtf(var + 1e-6f);
    float4 g4 = ((const float4*)g)[t];
    float4 b4 = ((const float4*)be)[t];
    float o0 = (v[0] - mu) * rs * g4.x + b4.x;
    float o1 = (v[1] - mu) * rs * g4.y + b4.y;
    float o2 = (v[2] - mu) * rs * g4.z + b4.z;
    float o3 = (v[3] - mu) * rs * g4.w + b4.w;
    if (outf) {
        int orow = map_row(m, omb, obsd, oro);
        ((float4*)(outf + (size_t)orow * ldo))[t] = make_float4(o0, o1, o2, o3);
    }
    if (outb) {
        int brow = map_row(m, bmb, bbsd, bro);
        ((ushort4*)(outb + (size_t)brow * ldb))[t] =
            make_ushort4(f2b(o0), f2b(o1), f2b(o2), f2b(o3));
    }
}

// ================= fp32 -> bf16 convert (n4 float4 groups)
__global__ void f2b_kernel(const float* __restrict__ in, unsigned short* __restrict__ out, int n4)
{
    int i = blockIdx.x * 256 + threadIdx.x;
    if (i >= n4) return;
    float4 v = ((const float4*)in)[i];
    ((ushort4*)out)[i] = make_ushort4(f2b(v.x), f2b(v.y), f2b(v.z), f2b(v.w));
}

// ================= merged 6-weight fp32 -> bf16 convert
struct W6 { const float* p[6]; };
__global__ void wconv_kernel(W6 w, unsigned short* __restrict__ out)
{
    const int cum[7] = {0, 262144, 524288, 655360, 786432, 1048576, 1310720};
    int i = blockIdx.x * 256 + threadIdx.x;
    if (i >= 1310720) return;
    int seg = 0;
    #pragma unroll
    for (int s = 1; s < 6; s++) seg += (i >= cum[s]);
    float4 v = ((const float4*)w.p[seg])[i - cum[seg]];
    ((ushort4*)out)[i] = make_ushort4(f2b(v.x), f2b(v.y), f2b(v.z), f2b(v.w));
}

// ================= memory(fp32) -> catb(bf16) rows [b*1536 + 0..1023]
__global__ void mem2catb_kernel(const float* __restrict__ mem, unsigned short* __restrict__ catb)
{
    int f = blockIdx.x * blockDim.x + threadIdx.x;
    const int total = BB * TTM * DM / 4;
    if (f >= total) return;
    const int per_b = TTM * DM / 4;
    int b = f / per_b, rem = f - b * per_b;
    float4 v = ((const float4*)mem)[f];
    ((ushort4*)catb)[(size_t)b * (LCAT * DM / 4) + rem] =
        make_ushort4(f2b(v.x), f2b(v.y), f2b(v.z), f2b(v.w));
}

static void run_scan(const unsigned short* dltb, const unsigned short* xcb, const float* bc,
                     const unsigned short* xzb, const float* A_log, const float* Dv,
                     float* part_h, float* part_s, unsigned short* out, int L,
                     hipStream_t stream)
{
    int CH = L / NC;
    int blocks = BB * NC * (DI / 256);
    scan_part1<<<blocks, 256, 0, stream>>>(dltb, xcb, bc, A_log, part_h, part_s, L, CH);
    scan_combine<<<BB * DI / 256, 256, 0, stream>>>(A_log, part_h, part_s);
    scan_part2<<<blocks, 256, 0, stream>>>(dltb, xcb, bc, xzb, A_log, Dv, part_h, out, L, CH);
}

extern "C" void kernel_launch(void* const* d_in, const int* in_sizes, int n_in,
                              void* d_out, int out_size, void* d_ws, size_t ws_size,
                              hipStream_t stream)
{
    const float* tgt       = (const float*)d_in[0];
    const float* memory    = (const float*)d_in[1];
    const float* s_in_w    = (const float*)d_in[2];
    const float* s_conv_w  = (const float*)d_in[3];
    const float* s_conv_b  = (const float*)d_in[4];
    const float* s_xproj_w = (const float*)d_in[5];
    const float* s_dt_w    = (const float*)d_in[6];
    const float* s_dt_b    = (const float*)d_in[7];
    const float* s_A_log   = (const float*)d_in[8];
    const float* s_D_vec   = (const float*)d_in[9];
    const float* s_out_w   = (const float*)d_in[10];
    const float* c_in_w    = (const float*)d_in[11];
    const float* c_conv_w  = (const float*)d_in[12];
    const float* c_conv_b  = (const float*)d_in[13];
    const float* c_xproj_w = (const float*)d_in[14];
    const float* c_dt_w    = (const float*)d_in[15];
    const float* c_dt_b    = (const float*)d_in[16];
    const float* c_A_log   = (const float*)d_in[17];
    const float* c_D_vec   = (const float*)d_in[18];
    const float* c_out_w   = (const float*)d_in[19];
    const float* ln1_g     = (const float*)d_in[20];
    const float* ln1_b     = (const float*)d_in[21];
    const float* ln2_g     = (const float*)d_in[22];
    const float* ln2_b     = (const float*)d_in[23];
    const float* ln3_g     = (const float*)d_in[24];
    const float* ln3_b     = (const float*)d_in[25];
    const float* ffn_w1    = (const float*)d_in[26];
    const float* ffn_b1    = (const float*)d_in[27];
    const float* ffn_w2    = (const float*)d_in[28];
    const float* ffn_b2    = (const float*)d_in[29];
    float* outp = (float*)d_out;

    // ---- workspace layout ----
    float* ws     = (float*)d_ws;
    float* bc     = ws;                     // 393216  (12288 x 32: B|C)
    float* proj   = bc     + 393216;        // 2097152
    float* proj2  = proj   + 2097152;       // 2097152 (split-K partial)
    float* t1     = proj2  + 2097152;       // 2097152
    float* tbuf   = t1     + 2097152;       // 2097152
    float* part_h = tbuf   + 2097152;       // 4194304
    float* part_s = part_h + 4194304;       // 262144
    unsigned short* ub      = (unsigned short*)(part_s + 262144);
    unsigned short* dltb    = ub;                   // 12582912 (bf16 delta; ffnout aliases)
    unsigned short* catb    = dltb    + 12582912;   // 6291456
    unsigned short* tgtb    = catb    + 6291456;    // 2097152
    unsigned short* xzb     = tgtb    + 2097152;    // 25165824 (also fbuf alias)
    unsigned short* xcb     = xzb     + 25165824;   // 12582912
    unsigned short* ygb     = xcb     + 12582912;   // 12582912
    unsigned short* tbbf    = ygb     + 12582912;   // 2097152
    unsigned short* s_in_wb = tbbf    + 2097152;    // 1048576  (6-weight block, contiguous)
    unsigned short* c_in_wb = s_in_wb + 1048576;    // 1048576
    unsigned short* s_out_wb= c_in_wb + 1048576;    // 524288
    unsigned short* c_out_wb= s_out_wb+ 524288;     // 524288
    unsigned short* w1b     = c_out_wb+ 524288;     // 1048576
    unsigned short* w2b     = w1b     + 1048576;    // 1048576
    unsigned short* wcomb_s = w2b     + 1048576;    // 1179648 (1152 x 1024)
    unsigned short* wcomb_c = wcomb_s + 1179648;    // 1179648
    unsigned short* fbuf    = xzb;                  // FFN hidden alias
    float* ffnout  = (float*)dltb;                  // alias (dltb dead after cross scan)
    float* ffnout2 = ffnout + 2097152;              // split-K partial (fits in dltb region)

    // ---- converts & combined-weight fills ----
    f2b_kernel<<<(2097152/4 + 255)/256, 256, 0, stream>>>(tgt, tgtb, 2097152/4);
    mem2catb_kernel<<<(BB*TTM*DM/4 + 255)/256, 256, 0, stream>>>(memory, catb);
    {
        W6 w; w.p[0]=s_in_w; w.p[1]=c_in_w; w.p[2]=s_out_w; w.p[3]=c_out_w; w.p[4]=ffn_w1; w.p[5]=ffn_w2;
        wconv_kernel<<<(1310720 + 255)/256, 256, 0, stream>>>(w, s_in_wb);
    }
    wcomb_kernel<<<(1152*1024)/256, 256, 0, stream>>>(s_dt_w, s_xproj_w, wcomb_s);
    wcomb_kernel<<<(1152*1024)/256, 256, 0, stream>>>(c_dt_w, c_xproj_w, wcomb_c);

    // ---- self mamba (L=512, M=4096) ----
    mgemm_kernel<<<dim3(2048/128, 4096/128), 256, 0, stream>>>(
        tgtb, 4096, 0, 0, s_in_wb, nullptr, nullptr, xzb, nullptr, nullptr, 2048, 512, ACT_NONE);
    conv_silu_kernel<<<(BB*SS*DI/8 + 255)/256, 256, 0, stream>>>(xzb, s_conv_w, s_conv_b, xcb, SS, BB*SS*DI/8);
    mgemm_kernel<<<dim3(1152/128, 4096/128), 256, 0, stream>>>(
        xcb, 4096, 0, 0, wcomb_s, s_dt_b, nullptr, dltb, bc, nullptr, 1152, 1024, ACT_DELTA);
    run_scan(dltb, xcb, bc, xzb, s_A_log, s_D_vec, part_h, part_s, ygb, SS, stream);
    mgemm_kernel<<<dim3(512/128, 4096/128, 2), 256, 0, stream>>>(
        ygb, 4096, 0, 0, s_out_wb, nullptr, proj, nullptr, nullptr, proj2, 512, 1024, ACT_NONE);
    addln_kernel<<<4096, 128, 0, stream>>>(
        tgt, 4096, 0, 0, DM, proj, proj2, ln1_g, ln1_b,
        t1, 4096, 0, 0, DM, catb, 512, 1536, 1024, DM);

    // ---- cross mamba (L=1536, M=12288) ----
    mgemm_kernel<<<dim3(2048/128, 12288/128), 256, 0, stream>>>(
        catb, 12288, 0, 0, c_in_wb, nullptr, nullptr, xzb, nullptr, nullptr, 2048, 512, ACT_NONE);
    conv_silu_kernel<<<(BB*LCAT*DI/8 + 255)/256, 256, 0, stream>>>(xzb, c_conv_w, c_conv_b, xcb, LCAT, BB*LCAT*DI/8);
    mgemm_kernel<<<dim3(1152/128, 12288/128), 256, 0, stream>>>(
        xcb, 12288, 0, 0, wcomb_c, c_dt_b, nullptr, dltb, bc, nullptr, 1152, 1024, ACT_DELTA);
    run_scan(dltb, xcb, bc, xzb, c_A_log, c_D_vec, part_h, part_s, ygb, LCAT, stream);
    mgemm_kernel<<<dim3(512/128, 4096/128, 2), 256, 0, stream>>>(
        ygb, 512, 1536, 1024, c_out_wb, nullptr, proj, nullptr, nullptr, proj2, 512, 1024, ACT_NONE);
    addln_kernel<<<4096, 128, 0, stream>>>(
        t1, 4096, 0, 0, DM, proj, proj2, ln2_g, ln2_b,
        tbuf, 4096, 0, 0, DM, tbbf, 4096, 0, 0, DM);

    // ---- FFN ----
    mgemm_kernel<<<dim3(2048/128, 4096/128), 256, 0, stream>>>(
        tbbf, 4096, 0, 0, w1b, ffn_b1, nullptr, fbuf, nullptr, nullptr, 2048, 512, ACT_RELU);
    mgemm_kernel<<<dim3(512/128, 4096/128, 2), 256, 0, stream>>>(
        fbuf, 4096, 0, 0, w2b, ffn_b2, ffnout, nullptr, nullptr, ffnout2, 512, 2048, ACT_NONE);
    addln_kernel<<<4096, 128, 0, stream>>>(
        tbuf, 4096, 0, 0, DM, ffnout, ffnout2, ln3_g, ln3_b,
        outp, 4096, 0, 0, DM, nullptr, 0, 0, 0, 0);
}

// Round 13
// 660.298 us; speedup vs baseline: 1.0677x; 1.0677x over previous
//
#include <hip/hip_runtime.h>
#include <math.h>

// Problem constants
#define DM    512
#define DI    1024
#define DSN   16
#define DTR   32
#define DFFN  2048
#define BB    8
#define SS    512
#define TTM   1024
#define LCAT  1536
#define NC    32      // scan chunks per sequence

#define ACT_NONE     0
#define ACT_RELU     1
#define ACT_DELTA    3   // split epilogue: n<1024 softplus+bias -> Cb(delta bf16); 1024<=n<1056 -> C2(bc fp32)

typedef __attribute__((ext_vector_type(8))) short short8;
typedef __attribute__((ext_vector_type(8))) unsigned short ushort8;
typedef __attribute__((ext_vector_type(4))) float f32x4;

__device__ __forceinline__ unsigned short f2b(float f) {
    unsigned int u = __float_as_uint(f);
    return (unsigned short)((u + 0x7FFFu + ((u >> 16) & 1u)) >> 16);
}
__device__ __forceinline__ float b2f(unsigned short h) {
    return __uint_as_float(((unsigned int)h) << 16);
}
__device__ __forceinline__ float fast_softplus(float v) {
    return (v > 20.f) ? v : __logf(1.f + __expf(v));
}
__device__ __forceinline__ void gld16(const void* g, void* l) {
    __builtin_amdgcn_global_load_lds(
        (const __attribute__((address_space(1))) void*)g,
        (__attribute__((address_space(3))) void*)l, 16, 0, 0);
}

__device__ __forceinline__ int map_row(int m, int mb, int bs, int ro) {
    int q = m / mb;
    return q * bs + ro + (m - q * mb);
}

// ================= bf16 MFMA GEMM: C[m,n] = act(A[row(m),k] * W[n,k] + bias[n])
// Tile 128x128, BK=64. R10's validated config (686us base, in-proj <59.5us):
//   - 2-bit quad XOR swizzle: chunk (r, g in 0..7) at p = r*8 + (g&4) +
//     ((g&3)^(r&3)). Staging quads stay in one 64B half-row (best coalescing);
//     read side pays 4-way quad conflicts (+4cyc/b128, ~5% of K-loop) — R11's
//     conflict-free 3-bit variant cost more in staging (82 vs 59.5us) and
//     R12's LDS-transpose epilogue cost more in VALU (74.5us). Scalar bf16
//     epilogue stores are absorbed by L2 write-combining.
// Split-K via gridDim.z==2 (fp32 out path): z=1 writes partials to Cf2, no bias.
__global__ __launch_bounds__(256) void mgemm_kernel(
    const unsigned short* __restrict__ A, int mb, int bs, int ro,
    const unsigned short* __restrict__ W, const float* __restrict__ bias,
    float* __restrict__ Cf, unsigned short* __restrict__ Cb,
    float* __restrict__ C2, float* __restrict__ Cf2,
    int N, int K, int act)
{
    __shared__ __align__(16) unsigned short As[128 * 64];
    __shared__ __align__(16) unsigned short Bs[128 * 64];
    int tid = threadIdx.x;
    int lane = tid & 63, wave = tid >> 6;
    int wy = wave >> 1, wx = wave & 1;
    // XCD-band swizzle over (x,y); z (split-K) reuses the same mapping
    int nx = gridDim.x;
    int f = blockIdx.y * nx + blockIdx.x;
    int xcd = f & 7, j2 = f >> 3;
    int bandh = gridDim.y >> 3;
    int m0 = (xcd * bandh + j2 / nx) * 128;
    int n0 = (j2 % nx) * 128;
    // split-K
    int Kh = K / gridDim.z;
    int kbeg = blockIdx.z * Kh, kend = kbeg + Kh;
    float* Cfo = Cf;
    const float* biaso = bias;
    if (blockIdx.z) { Cfo = Cf2; biaso = nullptr; }

    // staging: wave stages chunk positions c = wave*256 + j*64 + lane (j=0..3)
    const unsigned short* ga[4];
    const unsigned short* gb[4];
    unsigned short* la[4];
    unsigned short* lb[4];
    #pragma unroll
    for (int j = 0; j < 4; j++) {
        int c  = wave * 256 + j * 64 + lane;
        int r  = c >> 3;                    // tile row 0..127
        int q  = c & 7;
        int g  = (q & 4) | ((q & 3) ^ (r & 3));   // un-swizzled k-chunk 0..7
        int arow = map_row(m0 + r, mb, bs, ro);
        ga[j] = A + (size_t)arow * K + g * 8;
        gb[j] = W + (size_t)(n0 + r) * K + g * 8;
        la[j] = As + (size_t)(wave * 256 + j * 64) * 8;   // chunk pos * 8 shorts
        lb[j] = Bs + (size_t)(wave * 256 + j * 64) * 8;
    }
    // fragment read bases; R&3 == fm&3 (wy*64, t*16 are mult of 4)
    int fm = lane & 15, fg = lane >> 4;
    int sw = fg ^ (fm & 3);
    const unsigned short* arp = As + ((size_t)(wy * 64 + fm) * 8 + sw) * 8;
    const unsigned short* brp = Bs + ((size_t)(wx * 64 + fm) * 8 + sw) * 8;

    f32x4 acc[4][4];
    #pragma unroll
    for (int i = 0; i < 4; i++)
        #pragma unroll
        for (int j = 0; j < 4; j++) acc[i][j] = 0.f;

    for (int k0 = kbeg; k0 < kend; k0 += 64) {
        #pragma unroll
        for (int j = 0; j < 4; j++) {
            gld16(ga[j] + k0, la[j]);
            gld16(gb[j] + k0, lb[j]);
        }
        __syncthreads();
        #pragma unroll
        for (int h = 0; h < 2; h++) {
            short8 af[4], bfr[4];
            #pragma unroll
            for (int t = 0; t < 4; t++) af[t]  = *(const short8*)(arp + h * 32 + t * 1024);
            #pragma unroll
            for (int t = 0; t < 4; t++) bfr[t] = *(const short8*)(brp + h * 32 + t * 1024);
            #pragma unroll
            for (int i = 0; i < 4; i++)
                #pragma unroll
                for (int j = 0; j < 4; j++)
                    acc[i][j] = __builtin_amdgcn_mfma_f32_16x16x32_bf16(af[i], bfr[j], acc[i][j], 0, 0, 0);
        }
        __syncthreads();
    }

    // epilogue: C/D layout col=lane&15 (n), row=(lane>>4)*4+reg (m)
    int en = lane & 15, em = (lane >> 4) * 4;
    if (act == ACT_DELTA) {
        #pragma unroll
        for (int j = 0; j < 4; j++) {
            int n = n0 + wx * 64 + j * 16 + en;
            bool is_delta = (n < 1024);
            if (!is_delta && n >= 1056) continue;
            float bv = is_delta ? bias[n] : 0.f;
            #pragma unroll
            for (int i = 0; i < 4; i++) {
                int mbase = m0 + wy * 64 + i * 16 + em;
                #pragma unroll
                for (int r = 0; r < 4; r++) {
                    float v = acc[i][j][r] + bv;
                    if (is_delta) {
                        Cb[(size_t)(mbase + r) * 1024 + n] = f2b(fast_softplus(v));
                    } else {
                        C2[(size_t)(mbase + r) * 32 + (n - 1024)] = v;
                    }
                }
            }
        }
        return;
    }
    #pragma unroll
    for (int j = 0; j < 4; j++) {
        int n = n0 + wx * 64 + j * 16 + en;
        float bv = biaso ? biaso[n] : 0.f;
        #pragma unroll
        for (int i = 0; i < 4; i++) {
            int mbase = m0 + wy * 64 + i * 16 + em;
            #pragma unroll
            for (int r = 0; r < 4; r++) {
                float v = acc[i][j][r] + bv;
                if (act == ACT_RELU) v = v > 0.f ? v : 0.f;
                size_t off = (size_t)(mbase + r) * N + n;
                if (Cb) Cb[off] = f2b(v);
                else    Cfo[off] = v;
            }
        }
    }
}

// ================= Wcomb fill: rows 0..1023 = dt_w @ xproj[:32]; 1024..1055 = xproj rows 32..63; rest 0
__global__ void wcomb_kernel(const float* __restrict__ dt_w,
                             const float* __restrict__ xproj,
                             unsigned short* __restrict__ out)
{
    int idx = blockIdx.x * 256 + threadIdx.x;   // n*1024 + k, n < 1152
    int n = idx >> 10, k = idx & 1023;
    float v = 0.f;
    if (n < 1024) {
        #pragma unroll
        for (int r = 0; r < DTR; r++)
            v = fmaf(dt_w[n * DTR + r], xproj[r * 1024 + k], v);
    } else if (n < 1056) {
        v = xproj[(n - 1024 + 32) * 1024 + k];
    }
    out[idx] = f2b(v);
}

// ================= Depthwise causal conv (width 4) + bias + SiLU, ushort8-vectorized
__global__ __launch_bounds__(256) void conv_silu_kernel(
    const unsigned short* __restrict__ xz,
    const float* __restrict__ cw,
    const float* __restrict__ cb,
    unsigned short* __restrict__ xc, int L, int total8)
{
    int idx = blockIdx.x * blockDim.x + threadIdx.x;
    if (idx >= total8) return;
    int d8 = idx & 127;
    int d0 = d8 * 8;
    int r  = idx >> 7;             // b*L + l
    int l  = r % L;
    float acc[8];
    {
        float4 c0 = ((const float4*)(cb + d0))[0];
        float4 c1 = ((const float4*)(cb + d0))[1];
        acc[0]=c0.x; acc[1]=c0.y; acc[2]=c0.z; acc[3]=c0.w;
        acc[4]=c1.x; acc[5]=c1.y; acc[6]=c1.z; acc[7]=c1.w;
    }
    float4 wv[8];
    #pragma unroll
    for (int j = 0; j < 8; j++) wv[j] = *(const float4*)(cw + (d0 + j) * 4);
    #pragma unroll
    for (int k = 0; k < 4; k++) {
        int ls = l - 3 + k;
        if (ls >= 0) {
            ushort8 v = *(const ushort8*)(xz + (size_t)(r - 3 + k) * 2048 + d0);
            const float* w = (const float*)&wv[0];
            #pragma unroll
            for (int j = 0; j < 8; j++)
                acc[j] = fmaf(b2f(v[j]), w[j * 4 + k], acc[j]);
        }
    }
    ushort8 o;
    #pragma unroll
    for (int j = 0; j < 8; j++) {
        float s = acc[j] / (1.f + __expf(-acc[j]));
        o[j] = f2b(s);
    }
    *(ushort8*)(xc + (size_t)r * 1024 + d0) = o;
}

// ================= Chunked selective scan (delta bf16)
__global__ __launch_bounds__(256) void scan_part1(
    const unsigned short* __restrict__ delta, const unsigned short* __restrict__ xc,
    const float* __restrict__ bc, const float* __restrict__ A_log,
    float* __restrict__ part_h, float* __restrict__ part_s, int L, int CH)
{
    int tid = threadIdx.x;
    int dblk = blockIdx.x & 3;
    int c    = (blockIdx.x >> 2) & (NC - 1);
    int b    = blockIdx.x >> 7;
    int d    = dblk * 256 + tid;
    float A[DSN];
    #pragma unroll
    for (int s = 0; s < DSN; s++) A[s] = -__expf(A_log[d * DSN + s]);
    float h[DSN];
    #pragma unroll
    for (int s = 0; s < DSN; s++) h[s] = 0.f;
    float ssum = 0.f;
    int l0 = c * CH;
    for (int l = l0; l < l0 + CH; l++) {
        size_t r = (size_t)b * L + l;
        float4 bq[4];
        const float4* bp = (const float4*)(bc + r * 32);
        #pragma unroll
        for (int q = 0; q < 4; q++) bq[q] = bp[q];
        const float* Bm = (const float*)&bq[0];
        float dl = b2f(delta[r * DI + d]);
        float u  = b2f(xc[r * DI + d]);
        float du = dl * u;
        ssum += dl;
        #pragma unroll
        for (int s = 0; s < DSN; s++)
            h[s] = fmaf(__expf(dl * A[s]), h[s], du * Bm[s]);
    }
    size_t base = ((size_t)(b * NC + c) * DI + d) * DSN;
    #pragma unroll
    for (int q = 0; q < 4; q++)
        ((float4*)(part_h + base))[q] = make_float4(h[q*4], h[q*4+1], h[q*4+2], h[q*4+3]);
    part_s[(size_t)(b * NC + c) * DI + d] = ssum;
}

__global__ __launch_bounds__(256) void scan_combine(
    const float* __restrict__ A_log,
    float* __restrict__ part_h, const float* __restrict__ part_s)
{
    int idx = blockIdx.x * 256 + threadIdx.x;
    int b = idx >> 10, d = idx & (DI - 1);
    float A[DSN];
    #pragma unroll
    for (int s = 0; s < DSN; s++) A[s] = -__expf(A_log[d * DSN + s]);
    float h[DSN];
    #pragma unroll
    for (int s = 0; s < DSN; s++) h[s] = 0.f;
    for (int c = 0; c < NC; c++) {
        size_t base = ((size_t)(b * NC + c) * DI + d) * DSN;
        float4 ph4[4];
        #pragma unroll
        for (int q = 0; q < 4; q++) ph4[q] = ((const float4*)(part_h + base))[q];
        const float* ph = (const float*)&ph4[0];
        float S = part_s[(size_t)(b * NC + c) * DI + d];
        #pragma unroll
        for (int q = 0; q < 4; q++)
            ((float4*)(part_h + base))[q] = make_float4(h[q*4], h[q*4+1], h[q*4+2], h[q*4+3]);
        #pragma unroll
        for (int s = 0; s < DSN; s++)
            h[s] = fmaf(__expf(A[s] * S), h[s], ph[s]);
    }
}

__global__ __launch_bounds__(256) void scan_part2(
    const unsigned short* __restrict__ delta, const unsigned short* __restrict__ xc,
    const float* __restrict__ bc, const unsigned short* __restrict__ xz,
    const float* __restrict__ A_log, const float* __restrict__ Dv,
    const float* __restrict__ part_h,
    unsigned short* __restrict__ out, int L, int CH)
{
    int tid = threadIdx.x;
    int dblk = blockIdx.x & 3;
    int c    = (blockIdx.x >> 2) & (NC - 1);
    int b    = blockIdx.x >> 7;
    int d    = dblk * 256 + tid;
    float A[DSN];
    #pragma unroll
    for (int s = 0; s < DSN; s++) A[s] = -__expf(A_log[d * DSN + s]);
    float Dvd = Dv[d];
    size_t base = ((size_t)(b * NC + c) * DI + d) * DSN;
    float h4[4][4];
    #pragma unroll
    for (int q = 0; q < 4; q++) *((float4*)h4[q]) = ((const float4*)(part_h + base))[q];
    float h[DSN];
    #pragma unroll
    for (int s = 0; s < DSN; s++) h[s] = h4[s >> 2][s & 3];
    int l0 = c * CH;
    for (int l = l0; l < l0 + CH; l++) {
        size_t r = (size_t)b * L + l;
        float4 bq[8];
        const float4* bp = (const float4*)(bc + r * 32);
        #pragma unroll
        for (int q = 0; q < 8; q++) bq[q] = bp[q];
        const float* Bm = (const float*)&bq[0];
        const float* Cm = Bm + DSN;
        float dl = b2f(delta[r * DI + d]);
        float u  = b2f(xc[r * DI + d]);
        float du = dl * u;
        float y = 0.f;
        #pragma unroll
        for (int s = 0; s < DSN; s++) {
            h[s] = fmaf(__expf(dl * A[s]), h[s], du * Bm[s]);
            y = fmaf(h[s], Cm[s], y);
        }
        float z = b2f(xz[r * 2048 + DI + d]);
        float sil = z / (1.f + __expf(-z));
        out[r * DI + d] = f2b((y + u * Dvd) * sil);
    }
}

// ================= residual add + LayerNorm; a + bsrc (+ bsrc2); fp32/bf16 outs
__global__ __launch_bounds__(128) void addln_kernel(
    const float* __restrict__ a, int amb, int absd, int aro, int lda,
    const float* __restrict__ bsrc, const float* __restrict__ bsrc2,
    const float* __restrict__ g, const float* __restrict__ be,
    float* __restrict__ outf, int omb, int obsd, int oro, int ldo,
    unsigned short* __restrict__ outb, int bmb, int bbsd, int bro, int ldb)
{
    int m = blockIdx.x, t = threadIdx.x;
    int ar = map_row(m, amb, absd, aro);
    float4 x4 = ((const float4*)(a + (size_t)ar * lda))[t];
    float4 y4 = ((const float4*)(bsrc + (size_t)m * DM))[t];
    float v[4] = {x4.x + y4.x, x4.y + y4.y, x4.z + y4.z, x4.w + y4.w};
    if (bsrc2) {
        float4 z4 = ((const float4*)(bsrc2 + (size_t)m * DM))[t];
        v[0] += z4.x; v[1] += z4.y; v[2] += z4.z; v[3] += z4.w;
    }
    float sum = v[0] + v[1] + v[2] + v[3];
    float sq  = v[0]*v[0] + v[1]*v[1] + v[2]*v[2] + v[3]*v[3];
    #pragma unroll
    for (int o = 32; o > 0; o >>= 1) {
        sum += __shfl_down(sum, o);
        sq  += __shfl_down(sq, o);
    }
    __shared__ float s0[2], s1[2];
    if ((t & 63) == 0) { s0[t >> 6] = sum; s1[t >> 6] = sq; }
    __syncthreads();
    float tot = s0[0] + s0[1];
    float tsq = s1[0] + s1[1];
    float mu = tot * (1.f / DM);
    float var = tsq * (1.f / DM) - mu * mu;
    float rs = rsqrtf(var + 1e-6f);
    float4 g4 = ((const float4*)g)[t];
    float4 b4 = ((const float4*)be)[t];
    float o0 = (v[0] - mu) * rs * g4.x + b4.x;
    float o1 = (v[1] - mu) * rs * g4.y + b4.y;
    float o2 = (v[2] - mu) * rs * g4.z + b4.z;
    float o3 = (v[3] - mu) * rs * g4.w + b4.w;
    if (outf) {
        int orow = map_row(m, omb, obsd, oro);
        ((float4*)(outf + (size_t)orow * ldo))[t] = make_float4(o0, o1, o2, o3);
    }
    if (outb) {
        int brow = map_row(m, bmb, bbsd, bro);
        ((ushort4*)(outb + (size_t)brow * ldb))[t] =
            make_ushort4(f2b(o0), f2b(o1), f2b(o2), f2b(o3));
    }
}

// ================= fp32 -> bf16 convert (n4 float4 groups)
__global__ void f2b_kernel(const float* __restrict__ in, unsigned short* __restrict__ out, int n4)
{
    int i = blockIdx.x * 256 + threadIdx.x;
    if (i >= n4) return;
    float4 v = ((const float4*)in)[i];
    ((ushort4*)out)[i] = make_ushort4(f2b(v.x), f2b(v.y), f2b(v.z), f2b(v.w));
}

// ================= merged 6-weight fp32 -> bf16 convert
struct W6 { const float* p[6]; };
__global__ void wconv_kernel(W6 w, unsigned short* __restrict__ out)
{
    const int cum[7] = {0, 262144, 524288, 655360, 786432, 1048576, 1310720};
    int i = blockIdx.x * 256 + threadIdx.x;
    if (i >= 1310720) return;
    int seg = 0;
    #pragma unroll
    for (int s = 1; s < 6; s++) seg += (i >= cum[s]);
    float4 v = ((const float4*)w.p[seg])[i - cum[seg]];
    ((ushort4*)out)[i] = make_ushort4(f2b(v.x), f2b(v.y), f2b(v.z), f2b(v.w));
}

// ================= memory(fp32) -> catb(bf16) rows [b*1536 + 0..1023]
__global__ void mem2catb_kernel(const float* __restrict__ mem, unsigned short* __restrict__ catb)
{
    int f = blockIdx.x * blockDim.x + threadIdx.x;
    const int total = BB * TTM * DM / 4;
    if (f >= total) return;
    const int per_b = TTM * DM / 4;
    int b = f / per_b, rem = f - b * per_b;
    float4 v = ((const float4*)mem)[f];
    ((ushort4*)catb)[(size_t)b * (LCAT * DM / 4) + rem] =
        make_ushort4(f2b(v.x), f2b(v.y), f2b(v.z), f2b(v.w));
}

static void run_scan(const unsigned short* dltb, const unsigned short* xcb, const float* bc,
                     const unsigned short* xzb, const float* A_log, const float* Dv,
                     float* part_h, float* part_s, unsigned short* out, int L,
                     hipStream_t stream)
{
    int CH = L / NC;
    int blocks = BB * NC * (DI / 256);
    scan_part1<<<blocks, 256, 0, stream>>>(dltb, xcb, bc, A_log, part_h, part_s, L, CH);
    scan_combine<<<BB * DI / 256, 256, 0, stream>>>(A_log, part_h, part_s);
    scan_part2<<<blocks, 256, 0, stream>>>(dltb, xcb, bc, xzb, A_log, Dv, part_h, out, L, CH);
}

extern "C" void kernel_launch(void* const* d_in, const int* in_sizes, int n_in,
                              void* d_out, int out_size, void* d_ws, size_t ws_size,
                              hipStream_t stream)
{
    const float* tgt       = (const float*)d_in[0];
    const float* memory    = (const float*)d_in[1];
    const float* s_in_w    = (const float*)d_in[2];
    const float* s_conv_w  = (const float*)d_in[3];
    const float* s_conv_b  = (const float*)d_in[4];
    const float* s_xproj_w = (const float*)d_in[5];
    const float* s_dt_w    = (const float*)d_in[6];
    const float* s_dt_b    = (const float*)d_in[7];
    const float* s_A_log   = (const float*)d_in[8];
    const float* s_D_vec   = (const float*)d_in[9];
    const float* s_out_w   = (const float*)d_in[10];
    const float* c_in_w    = (const float*)d_in[11];
    const float* c_conv_w  = (const float*)d_in[12];
    const float* c_conv_b  = (const float*)d_in[13];
    const float* c_xproj_w = (const float*)d_in[14];
    const float* c_dt_w    = (const float*)d_in[15];
    const float* c_dt_b    = (const float*)d_in[16];
    const float* c_A_log   = (const float*)d_in[17];
    const float* c_D_vec   = (const float*)d_in[18];
    const float* c_out_w   = (const float*)d_in[19];
    const float* ln1_g     = (const float*)d_in[20];
    const float* ln1_b     = (const float*)d_in[21];
    const float* ln2_g     = (const float*)d_in[22];
    const float* ln2_b     = (const float*)d_in[23];
    const float* ln3_g     = (const float*)d_in[24];
    const float* ln3_b     = (const float*)d_in[25];
    const float* ffn_w1    = (const float*)d_in[26];
    const float* ffn_b1    = (const float*)d_in[27];
    const float* ffn_w2    = (const float*)d_in[28];
    const float* ffn_b2    = (const float*)d_in[29];
    float* outp = (float*)d_out;

    // ---- workspace layout ----
    float* ws     = (float*)d_ws;
    float* bc     = ws;                     // 393216  (12288 x 32: B|C)
    float* proj   = bc     + 393216;        // 2097152
    float* proj2  = proj   + 2097152;       // 2097152 (split-K partial)
    float* t1     = proj2  + 2097152;       // 2097152
    float* tbuf   = t1     + 2097152;       // 2097152
    float* part_h = tbuf   + 2097152;       // 4194304
    float* part_s = part_h + 4194304;       // 262144
    unsigned short* ub      = (unsigned short*)(part_s + 262144);
    unsigned short* dltb    = ub;                   // 12582912 (bf16 delta; ffnout aliases)
    unsigned short* catb    = dltb    + 12582912;   // 6291456
    unsigned short* tgtb    = catb    + 6291456;    // 2097152
    unsigned short* xzb     = tgtb    + 2097152;    // 25165824 (also fbuf alias)
    unsigned short* xcb     = xzb     + 25165824;   // 12582912
    unsigned short* ygb     = xcb     + 12582912;   // 12582912
    unsigned short* tbbf    = ygb     + 12582912;   // 2097152
    unsigned short* s_in_wb = tbbf    + 2097152;    // 1048576  (6-weight block, contiguous)
    unsigned short* c_in_wb = s_in_wb + 1048576;    // 1048576
    unsigned short* s_out_wb= c_in_wb + 1048576;    // 524288
    unsigned short* c_out_wb= s_out_wb+ 524288;     // 524288
    unsigned short* w1b     = c_out_wb+ 524288;     // 1048576
    unsigned short* w2b     = w1b     + 1048576;    // 1048576
    unsigned short* wcomb_s = w2b     + 1048576;    // 1179648 (1152 x 1024)
    unsigned short* wcomb_c = wcomb_s + 1179648;    // 1179648
    unsigned short* fbuf    = xzb;                  // FFN hidden alias
    float* ffnout  = (float*)dltb;                  // alias (dltb dead after cross scan)
    float* ffnout2 = ffnout + 2097152;              // split-K partial (fits in dltb region)

    // ---- converts & combined-weight fills ----
    f2b_kernel<<<(2097152/4 + 255)/256, 256, 0, stream>>>(tgt, tgtb, 2097152/4);
    mem2catb_kernel<<<(BB*TTM*DM/4 + 255)/256, 256, 0, stream>>>(memory, catb);
    {
        W6 w; w.p[0]=s_in_w; w.p[1]=c_in_w; w.p[2]=s_out_w; w.p[3]=c_out_w; w.p[4]=ffn_w1; w.p[5]=ffn_w2;
        wconv_kernel<<<(1310720 + 255)/256, 256, 0, stream>>>(w, s_in_wb);
    }
    wcomb_kernel<<<(1152*1024)/256, 256, 0, stream>>>(s_dt_w, s_xproj_w, wcomb_s);
    wcomb_kernel<<<(1152*1024)/256, 256, 0, stream>>>(c_dt_w, c_xproj_w, wcomb_c);

    // ---- self mamba (L=512, M=4096) ----
    mgemm_kernel<<<dim3(2048/128, 4096/128), 256, 0, stream>>>(
        tgtb, 4096, 0, 0, s_in_wb, nullptr, nullptr, xzb, nullptr, nullptr, 2048, 512, ACT_NONE);
    conv_silu_kernel<<<(BB*SS*DI/8 + 255)/256, 256, 0, stream>>>(xzb, s_conv_w, s_conv_b, xcb, SS, BB*SS*DI/8);
    mgemm_kernel<<<dim3(1152/128, 4096/128), 256, 0, stream>>>(
        xcb, 4096, 0, 0, wcomb_s, s_dt_b, nullptr, dltb, bc, nullptr, 1152, 1024, ACT_DELTA);
    run_scan(dltb, xcb, bc, xzb, s_A_log, s_D_vec, part_h, part_s, ygb, SS, stream);
    mgemm_kernel<<<dim3(512/128, 4096/128, 2), 256, 0, stream>>>(
        ygb, 4096, 0, 0, s_out_wb, nullptr, proj, nullptr, nullptr, proj2, 512, 1024, ACT_NONE);
    addln_kernel<<<4096, 128, 0, stream>>>(
        tgt, 4096, 0, 0, DM, proj, proj2, ln1_g, ln1_b,
        t1, 4096, 0, 0, DM, catb, 512, 1536, 1024, DM);

    // ---- cross mamba (L=1536, M=12288) ----
    mgemm_kernel<<<dim3(2048/128, 12288/128), 256, 0, stream>>>(
        catb, 12288, 0, 0, c_in_wb, nullptr, nullptr, xzb, nullptr, nullptr, 2048, 512, ACT_NONE);
    conv_silu_kernel<<<(BB*LCAT*DI/8 + 255)/256, 256, 0, stream>>>(xzb, c_conv_w, c_conv_b, xcb, LCAT, BB*LCAT*DI/8);
    mgemm_kernel<<<dim3(1152/128, 12288/128), 256, 0, stream>>>(
        xcb, 12288, 0, 0, wcomb_c, c_dt_b, nullptr, dltb, bc, nullptr, 1152, 1024, ACT_DELTA);
    run_scan(dltb, xcb, bc, xzb, c_A_log, c_D_vec, part_h, part_s, ygb, LCAT, stream);
    mgemm_kernel<<<dim3(512/128, 4096/128, 2), 256, 0, stream>>>(
        ygb, 512, 1536, 1024, c_out_wb, nullptr, proj, nullptr, nullptr, proj2, 512, 1024, ACT_NONE);
    addln_kernel<<<4096, 128, 0, stream>>>(
        t1, 4096, 0, 0, DM, proj, proj2, ln2_g, ln2_b,
        tbuf, 4096, 0, 0, DM, tbbf, 4096, 0, 0, DM);

    // ---- FFN ----
    mgemm_kernel<<<dim3(2048/128, 4096/128), 256, 0, stream>>>(
        tbbf, 4096, 0, 0, w1b, ffn_b1, nullptr, fbuf, nullptr, nullptr, 2048, 512, ACT_RELU);
    mgemm_kernel<<<dim3(512/128, 4096/128, 2), 256, 0, stream>>>(
        fbuf, 4096, 0, 0, w2b, ffn_b2, ffnout, nullptr, nullptr, ffnout2, 512, 2048, ACT_NONE);
    addln_kernel<<<4096, 128, 0, stream>>>(
        tbuf, 4096, 0, 0, DM, ffnout, ffnout2, ln3_g, ln3_b,
        outp, 4096, 0, 0, DM, nullptr, 0, 0, 0, 0);
}

// Round 14
// 638.719 us; speedup vs baseline: 1.1038x; 1.0338x over previous
//
#include <hip/hip_runtime.h>
#include <math.h>

// Problem constants
#define DM    512
#define DI    1024
#define DSN   16
#define DTR   32
#define DFFN  2048
#define BB    8
#define SS    512
#define TTM   1024
#define LCAT  1536
#define NC    32      // scan chunks per sequence

#define ACT_NONE     0
#define ACT_RELU     1
#define ACT_DELTA    3   // softplus+bias -> Cb(delta bf16, stride 1024)
#define ACT_XDBL     4   // n<32 -> dtb bf16 (stride 64); 32<=n<64 -> bc fp32 + zero dtb pad

typedef __attribute__((ext_vector_type(8))) short short8;
typedef __attribute__((ext_vector_type(8))) unsigned short ushort8;
typedef __attribute__((ext_vector_type(4))) float f32x4;

__device__ __forceinline__ unsigned short f2b(float f) {
    unsigned int u = __float_as_uint(f);
    return (unsigned short)((u + 0x7FFFu + ((u >> 16) & 1u)) >> 16);
}
__device__ __forceinline__ float b2f(unsigned short h) {
    return __uint_as_float(((unsigned int)h) << 16);
}
__device__ __forceinline__ float fast_softplus(float v) {
    return (v > 20.f) ? v : __logf(1.f + __expf(v));
}
__device__ __forceinline__ void gld16(const void* g, void* l) {
    __builtin_amdgcn_global_load_lds(
        (const __attribute__((address_space(1))) void*)g,
        (__attribute__((address_space(3))) void*)l, 16, 0, 0);
}

__device__ __forceinline__ int map_row(int m, int mb, int bs, int ro) {
    int q = m / mb;
    return q * bs + ro + (m - q * mb);
}

// ================= bf16 MFMA GEMM: C[m,n] = act(A[row(m),k] * W[n,k] + bias[n])
// Tile 128x128, BK=64. R10's validated config: 2-bit quad XOR swizzle
// (p = r*8 + (g&4) + ((g&3)^(r&3))) — best staging coalescing; accept 4-way
// quad read conflicts. Scalar bf16 epilogue stores (L2 write-combined).
// Split-K via gridDim.z==2 (fp32 out path): z=1 writes partials to Cf2, no bias.
__global__ __launch_bounds__(256) void mgemm_kernel(
    const unsigned short* __restrict__ A, int mb, int bs, int ro,
    const unsigned short* __restrict__ W, const float* __restrict__ bias,
    float* __restrict__ Cf, unsigned short* __restrict__ Cb,
    float* __restrict__ C2, float* __restrict__ Cf2,
    int N, int K, int act)
{
    __shared__ __align__(16) unsigned short As[128 * 64];
    __shared__ __align__(16) unsigned short Bs[128 * 64];
    int tid = threadIdx.x;
    int lane = tid & 63, wave = tid >> 6;
    int wy = wave >> 1, wx = wave & 1;
    // XCD-band swizzle over (x,y); z (split-K) reuses the same mapping
    int nx = gridDim.x;
    int f = blockIdx.y * nx + blockIdx.x;
    int xcd = f & 7, j2 = f >> 3;
    int bandh = gridDim.y >> 3;
    int m0 = (xcd * bandh + j2 / nx) * 128;
    int n0 = (j2 % nx) * 128;
    // split-K
    int Kh = K / gridDim.z;
    int kbeg = blockIdx.z * Kh, kend = kbeg + Kh;
    float* Cfo = Cf;
    const float* biaso = bias;
    if (blockIdx.z) { Cfo = Cf2; biaso = nullptr; }

    // staging: wave stages chunk positions c = wave*256 + j*64 + lane (j=0..3)
    const unsigned short* ga[4];
    const unsigned short* gb[4];
    unsigned short* la[4];
    unsigned short* lb[4];
    #pragma unroll
    for (int j = 0; j < 4; j++) {
        int c  = wave * 256 + j * 64 + lane;
        int r  = c >> 3;                    // tile row 0..127
        int q  = c & 7;
        int g  = (q & 4) | ((q & 3) ^ (r & 3));   // un-swizzled k-chunk 0..7
        int arow = map_row(m0 + r, mb, bs, ro);
        ga[j] = A + (size_t)arow * K + g * 8;
        gb[j] = W + (size_t)(n0 + r) * K + g * 8;
        la[j] = As + (size_t)(wave * 256 + j * 64) * 8;   // chunk pos * 8 shorts
        lb[j] = Bs + (size_t)(wave * 256 + j * 64) * 8;
    }
    // fragment read bases; R&3 == fm&3 (wy*64, t*16 are mult of 4)
    int fm = lane & 15, fg = lane >> 4;
    int sw = fg ^ (fm & 3);
    const unsigned short* arp = As + ((size_t)(wy * 64 + fm) * 8 + sw) * 8;
    const unsigned short* brp = Bs + ((size_t)(wx * 64 + fm) * 8 + sw) * 8;

    f32x4 acc[4][4];
    #pragma unroll
    for (int i = 0; i < 4; i++)
        #pragma unroll
        for (int j = 0; j < 4; j++) acc[i][j] = 0.f;

    for (int k0 = kbeg; k0 < kend; k0 += 64) {
        #pragma unroll
        for (int j = 0; j < 4; j++) {
            gld16(ga[j] + k0, la[j]);
            gld16(gb[j] + k0, lb[j]);
        }
        __syncthreads();
        #pragma unroll
        for (int h = 0; h < 2; h++) {
            short8 af[4], bfr[4];
            #pragma unroll
            for (int t = 0; t < 4; t++) af[t]  = *(const short8*)(arp + h * 32 + t * 1024);
            #pragma unroll
            for (int t = 0; t < 4; t++) bfr[t] = *(const short8*)(brp + h * 32 + t * 1024);
            #pragma unroll
            for (int i = 0; i < 4; i++)
                #pragma unroll
                for (int j = 0; j < 4; j++)
                    acc[i][j] = __builtin_amdgcn_mfma_f32_16x16x32_bf16(af[i], bfr[j], acc[i][j], 0, 0, 0);
        }
        __syncthreads();
    }

    // epilogue: C/D layout col=lane&15 (n), row=(lane>>4)*4+reg (m)
    int en = lane & 15, em = (lane >> 4) * 4;
    if (act == ACT_XDBL) {
        // GEMM1 of delta path: n<32 -> dt bf16 (Cb, stride 64);
        // 32<=n<64 -> bc fp32 (C2) AND zero dtb padding; n>=64 -> discard.
        #pragma unroll
        for (int j = 0; j < 4; j++) {
            int n = n0 + wx * 64 + j * 16 + en;
            if (n >= 64) continue;
            #pragma unroll
            for (int i = 0; i < 4; i++) {
                int mbase = m0 + wy * 64 + i * 16 + em;
                #pragma unroll
                for (int r = 0; r < 4; r++) {
                    float v = acc[i][j][r];
                    int m = mbase + r;
                    if (n < 32) {
                        Cb[(size_t)m * 64 + n] = f2b(v);
                    } else {
                        C2[(size_t)m * 32 + (n - 32)] = v;
                        Cb[(size_t)m * 64 + n] = 0;   // zero dtb pad (ws is poisoned)
                    }
                }
            }
        }
        return;
    }
    if (act == ACT_DELTA) {
        #pragma unroll
        for (int j = 0; j < 4; j++) {
            int n = n0 + wx * 64 + j * 16 + en;
            float bv = bias[n];
            #pragma unroll
            for (int i = 0; i < 4; i++) {
                int mbase = m0 + wy * 64 + i * 16 + em;
                #pragma unroll
                for (int r = 0; r < 4; r++) {
                    float v = acc[i][j][r] + bv;
                    Cb[(size_t)(mbase + r) * 1024 + n] = f2b(fast_softplus(v));
                }
            }
        }
        return;
    }
    #pragma unroll
    for (int j = 0; j < 4; j++) {
        int n = n0 + wx * 64 + j * 16 + en;
        float bv = biaso ? biaso[n] : 0.f;
        #pragma unroll
        for (int i = 0; i < 4; i++) {
            int mbase = m0 + wy * 64 + i * 16 + em;
            #pragma unroll
            for (int r = 0; r < 4; r++) {
                float v = acc[i][j][r] + bv;
                if (act == ACT_RELU) v = v > 0.f ? v : 0.f;
                size_t off = (size_t)(mbase + r) * N + n;
                if (Cb) Cb[off] = f2b(v);
                else    Cfo[off] = v;
            }
        }
    }
}

// ================= weight-pad fills for the two-stage delta path
// xprojb: 128x1024 bf16, rows 0..63 = xproj (64x1024), rows 64..127 = 0
__global__ void xprojb_fill(const float* __restrict__ xproj, unsigned short* __restrict__ out)
{
    int idx = blockIdx.x * 256 + threadIdx.x;   // 131072
    if (idx >= 131072) return;
    int n = idx >> 10;
    out[idx] = (n < 64) ? f2b(xproj[idx]) : (unsigned short)0;
}
// dtwb: 1024x64 bf16, cols 0..31 = dt_w (1024x32), cols 32..63 = 0
__global__ void dtwb_fill(const float* __restrict__ dt_w, unsigned short* __restrict__ out)
{
    int idx = blockIdx.x * 256 + threadIdx.x;   // 65536
    if (idx >= 65536) return;
    int n = idx >> 6, c = idx & 63;
    out[idx] = (c < 32) ? f2b(dt_w[n * 32 + c]) : (unsigned short)0;
}

// ================= Depthwise causal conv (width 4) + bias + SiLU, ushort8-vectorized
__global__ __launch_bounds__(256) void conv_silu_kernel(
    const unsigned short* __restrict__ xz,
    const float* __restrict__ cw,
    const float* __restrict__ cb,
    unsigned short* __restrict__ xc, int L, int total8)
{
    int idx = blockIdx.x * blockDim.x + threadIdx.x;
    if (idx >= total8) return;
    int d8 = idx & 127;
    int d0 = d8 * 8;
    int r  = idx >> 7;             // b*L + l
    int l  = r % L;
    float acc[8];
    {
        float4 c0 = ((const float4*)(cb + d0))[0];
        float4 c1 = ((const float4*)(cb + d0))[1];
        acc[0]=c0.x; acc[1]=c0.y; acc[2]=c0.z; acc[3]=c0.w;
        acc[4]=c1.x; acc[5]=c1.y; acc[6]=c1.z; acc[7]=c1.w;
    }
    float4 wv[8];
    #pragma unroll
    for (int j = 0; j < 8; j++) wv[j] = *(const float4*)(cw + (d0 + j) * 4);
    #pragma unroll
    for (int k = 0; k < 4; k++) {
        int ls = l - 3 + k;
        if (ls >= 0) {
            ushort8 v = *(const ushort8*)(xz + (size_t)(r - 3 + k) * 2048 + d0);
            const float* w = (const float*)&wv[0];
            #pragma unroll
            for (int j = 0; j < 8; j++)
                acc[j] = fmaf(b2f(v[j]), w[j * 4 + k], acc[j]);
        }
    }
    ushort8 o;
    #pragma unroll
    for (int j = 0; j < 8; j++) {
        float s = acc[j] / (1.f + __expf(-acc[j]));
        o[j] = f2b(s);
    }
    *(ushort8*)(xc + (size_t)r * 1024 + d0) = o;
}

// ================= Chunked selective scan (delta bf16)
__global__ __launch_bounds__(256) void scan_part1(
    const unsigned short* __restrict__ delta, const unsigned short* __restrict__ xc,
    const float* __restrict__ bc, const float* __restrict__ A_log,
    float* __restrict__ part_h, float* __restrict__ part_s, int L, int CH)
{
    int tid = threadIdx.x;
    int dblk = blockIdx.x & 3;
    int c    = (blockIdx.x >> 2) & (NC - 1);
    int b    = blockIdx.x >> 7;
    int d    = dblk * 256 + tid;
    float A[DSN];
    #pragma unroll
    for (int s = 0; s < DSN; s++) A[s] = -__expf(A_log[d * DSN + s]);
    float h[DSN];
    #pragma unroll
    for (int s = 0; s < DSN; s++) h[s] = 0.f;
    float ssum = 0.f;
    int l0 = c * CH;
    for (int l = l0; l < l0 + CH; l++) {
        size_t r = (size_t)b * L + l;
        float4 bq[4];
        const float4* bp = (const float4*)(bc + r * 32);
        #pragma unroll
        for (int q = 0; q < 4; q++) bq[q] = bp[q];
        const float* Bm = (const float*)&bq[0];
        float dl = b2f(delta[r * DI + d]);
        float u  = b2f(xc[r * DI + d]);
        float du = dl * u;
        ssum += dl;
        #pragma unroll
        for (int s = 0; s < DSN; s++)
            h[s] = fmaf(__expf(dl * A[s]), h[s], du * Bm[s]);
    }
    size_t base = ((size_t)(b * NC + c) * DI + d) * DSN;
    #pragma unroll
    for (int q = 0; q < 4; q++)
        ((float4*)(part_h + base))[q] = make_float4(h[q*4], h[q*4+1], h[q*4+2], h[q*4+3]);
    part_s[(size_t)(b * NC + c) * DI + d] = ssum;
}

__global__ __launch_bounds__(256) void scan_combine(
    const float* __restrict__ A_log,
    float* __restrict__ part_h, const float* __restrict__ part_s)
{
    int idx = blockIdx.x * 256 + threadIdx.x;
    int b = idx >> 10, d = idx & (DI - 1);
    float A[DSN];
    #pragma unroll
    for (int s = 0; s < DSN; s++) A[s] = -__expf(A_log[d * DSN + s]);
    float h[DSN];
    #pragma unroll
    for (int s = 0; s < DSN; s++) h[s] = 0.f;
    for (int c = 0; c < NC; c++) {
        size_t base = ((size_t)(b * NC + c) * DI + d) * DSN;
        float4 ph4[4];
        #pragma unroll
        for (int q = 0; q < 4; q++) ph4[q] = ((const float4*)(part_h + base))[q];
        const float* ph = (const float*)&ph4[0];
        float S = part_s[(size_t)(b * NC + c) * DI + d];
        #pragma unroll
        for (int q = 0; q < 4; q++)
            ((float4*)(part_h + base))[q] = make_float4(h[q*4], h[q*4+1], h[q*4+2], h[q*4+3]);
        #pragma unroll
        for (int s = 0; s < DSN; s++)
            h[s] = fmaf(__expf(A[s] * S), h[s], ph[s]);
    }
}

__global__ __launch_bounds__(256) void scan_part2(
    const unsigned short* __restrict__ delta, const unsigned short* __restrict__ xc,
    const float* __restrict__ bc, const unsigned short* __restrict__ xz,
    const float* __restrict__ A_log, const float* __restrict__ Dv,
    const float* __restrict__ part_h,
    unsigned short* __restrict__ out, int L, int CH)
{
    int tid = threadIdx.x;
    int dblk = blockIdx.x & 3;
    int c    = (blockIdx.x >> 2) & (NC - 1);
    int b    = blockIdx.x >> 7;
    int d    = dblk * 256 + tid;
    float A[DSN];
    #pragma unroll
    for (int s = 0; s < DSN; s++) A[s] = -__expf(A_log[d * DSN + s]);
    float Dvd = Dv[d];
    size_t base = ((size_t)(b * NC + c) * DI + d) * DSN;
    float h4[4][4];
    #pragma unroll
    for (int q = 0; q < 4; q++) *((float4*)h4[q]) = ((const float4*)(part_h + base))[q];
    float h[DSN];
    #pragma unroll
    for (int s = 0; s < DSN; s++) h[s] = h4[s >> 2][s & 3];
    int l0 = c * CH;
    for (int l = l0; l < l0 + CH; l++) {
        size_t r = (size_t)b * L + l;
        float4 bq[8];
        const float4* bp = (const float4*)(bc + r * 32);
        #pragma unroll
        for (int q = 0; q < 8; q++) bq[q] = bp[q];
        const float* Bm = (const float*)&bq[0];
        const float* Cm = Bm + DSN;
        float dl = b2f(delta[r * DI + d]);
        float u  = b2f(xc[r * DI + d]);
        float du = dl * u;
        float y = 0.f;
        #pragma unroll
        for (int s = 0; s < DSN; s++) {
            h[s] = fmaf(__expf(dl * A[s]), h[s], du * Bm[s]);
            y = fmaf(h[s], Cm[s], y);
        }
        float z = b2f(xz[r * 2048 + DI + d]);
        float sil = z / (1.f + __expf(-z));
        out[r * DI + d] = f2b((y + u * Dvd) * sil);
    }
}

// ================= residual add + LayerNorm; a + bsrc (+ bsrc2); fp32/bf16 outs
__global__ __launch_bounds__(128) void addln_kernel(
    const float* __restrict__ a, int amb, int absd, int aro, int lda,
    const float* __restrict__ bsrc, const float* __restrict__ bsrc2,
    const float* __restrict__ g, const float* __restrict__ be,
    float* __restrict__ outf, int omb, int obsd, int oro, int ldo,
    unsigned short* __restrict__ outb, int bmb, int bbsd, int bro, int ldb)
{
    int m = blockIdx.x, t = threadIdx.x;
    int ar = map_row(m, amb, absd, aro);
    float4 x4 = ((const float4*)(a + (size_t)ar * lda))[t];
    float4 y4 = ((const float4*)(bsrc + (size_t)m * DM))[t];
    float v[4] = {x4.x + y4.x, x4.y + y4.y, x4.z + y4.z, x4.w + y4.w};
    if (bsrc2) {
        float4 z4 = ((const float4*)(bsrc2 + (size_t)m * DM))[t];
        v[0] += z4.x; v[1] += z4.y; v[2] += z4.z; v[3] += z4.w;
    }
    float sum = v[0] + v[1] + v[2] + v[3];
    float sq  = v[0]*v[0] + v[1]*v[1] + v[2]*v[2] + v[3]*v[3];
    #pragma unroll
    for (int o = 32; o > 0; o >>= 1) {
        sum += __shfl_down(sum, o);
        sq  += __shfl_down(sq, o);
    }
    __shared__ float s0[2], s1[2];
    if ((t & 63) == 0) { s0[t >> 6] = sum; s1[t >> 6] = sq; }
    __syncthreads();
    float tot = s0[0] + s0[1];
    float tsq = s1[0] + s1[1];
    float mu = tot * (1.f / DM);
    float var = tsq * (1.f / DM) - mu * mu;
    float rs = rsqrtf(var + 1e-6f);
    float4 g4 = ((const float4*)g)[t];
    float4 b4 = ((const float4*)be)[t];
    float o0 = (v[0] - mu) * rs * g4.x + b4.x;
    float o1 = (v[1] - mu) * rs * g4.y + b4.y;
    float o2 = (v[2] - mu) * rs * g4.z + b4.z;
    float o3 = (v[3] - mu) * rs * g4.w + b4.w;
    if (outf) {
        int orow = map_row(m, omb, obsd, oro);
        ((float4*)(outf + (size_t)orow * ldo))[t] = make_float4(o0, o1, o2, o3);
    }
    if (outb) {
        int brow = map_row(m, bmb, bbsd, bro);
        ((ushort4*)(outb + (size_t)brow * ldb))[t] =
            make_ushort4(f2b(o0), f2b(o1), f2b(o2), f2b(o3));
    }
}

// ================= fp32 -> bf16 convert (n4 float4 groups)
__global__ void f2b_kernel(const float* __restrict__ in, unsigned short* __restrict__ out, int n4)
{
    int i = blockIdx.x * 256 + threadIdx.x;
    if (i >= n4) return;
    float4 v = ((const float4*)in)[i];
    ((ushort4*)out)[i] = make_ushort4(f2b(v.x), f2b(v.y), f2b(v.z), f2b(v.w));
}

// ================= merged 6-weight fp32 -> bf16 convert
struct W6 { const float* p[6]; };
__global__ void wconv_kernel(W6 w, unsigned short* __restrict__ out)
{
    const int cum[7] = {0, 262144, 524288, 655360, 786432, 1048576, 1310720};
    int i = blockIdx.x * 256 + threadIdx.x;
    if (i >= 1310720) return;
    int seg = 0;
    #pragma unroll
    for (int s = 1; s < 6; s++) seg += (i >= cum[s]);
    float4 v = ((const float4*)w.p[seg])[i - cum[seg]];
    ((ushort4*)out)[i] = make_ushort4(f2b(v.x), f2b(v.y), f2b(v.z), f2b(v.w));
}

// ================= memory(fp32) -> catb(bf16) rows [b*1536 + 0..1023]
__global__ void mem2catb_kernel(const float* __restrict__ mem, unsigned short* __restrict__ catb)
{
    int f = blockIdx.x * blockDim.x + threadIdx.x;
    const int total = BB * TTM * DM / 4;
    if (f >= total) return;
    const int per_b = TTM * DM / 4;
    int b = f / per_b, rem = f - b * per_b;
    float4 v = ((const float4*)mem)[f];
    ((ushort4*)catb)[(size_t)b * (LCAT * DM / 4) + rem] =
        make_ushort4(f2b(v.x), f2b(v.y), f2b(v.z), f2b(v.w));
}

static void run_scan(const unsigned short* dltb, const unsigned short* xcb, const float* bc,
                     const unsigned short* xzb, const float* A_log, const float* Dv,
                     float* part_h, float* part_s, unsigned short* out, int L,
                     hipStream_t stream)
{
    int CH = L / NC;
    int blocks = BB * NC * (DI / 256);
    scan_part1<<<blocks, 256, 0, stream>>>(dltb, xcb, bc, A_log, part_h, part_s, L, CH);
    scan_combine<<<BB * DI / 256, 256, 0, stream>>>(A_log, part_h, part_s);
    scan_part2<<<blocks, 256, 0, stream>>>(dltb, xcb, bc, xzb, A_log, Dv, part_h, out, L, CH);
}

extern "C" void kernel_launch(void* const* d_in, const int* in_sizes, int n_in,
                              void* d_out, int out_size, void* d_ws, size_t ws_size,
                              hipStream_t stream)
{
    const float* tgt       = (const float*)d_in[0];
    const float* memory    = (const float*)d_in[1];
    const float* s_in_w    = (const float*)d_in[2];
    const float* s_conv_w  = (const float*)d_in[3];
    const float* s_conv_b  = (const float*)d_in[4];
    const float* s_xproj_w = (const float*)d_in[5];
    const float* s_dt_w    = (const float*)d_in[6];
    const float* s_dt_b    = (const float*)d_in[7];
    const float* s_A_log   = (const float*)d_in[8];
    const float* s_D_vec   = (const float*)d_in[9];
    const float* s_out_w   = (const float*)d_in[10];
    const float* c_in_w    = (const float*)d_in[11];
    const float* c_conv_w  = (const float*)d_in[12];
    const float* c_conv_b  = (const float*)d_in[13];
    const float* c_xproj_w = (const float*)d_in[14];
    const float* c_dt_w    = (const float*)d_in[15];
    const float* c_dt_b    = (const float*)d_in[16];
    const float* c_A_log   = (const float*)d_in[17];
    const float* c_D_vec   = (const float*)d_in[18];
    const float* c_out_w   = (const float*)d_in[19];
    const float* ln1_g     = (const float*)d_in[20];
    const float* ln1_b     = (const float*)d_in[21];
    const float* ln2_g     = (const float*)d_in[22];
    const float* ln2_b     = (const float*)d_in[23];
    const float* ln3_g     = (const float*)d_in[24];
    const float* ln3_b     = (const float*)d_in[25];
    const float* ffn_w1    = (const float*)d_in[26];
    const float* ffn_b1    = (const float*)d_in[27];
    const float* ffn_w2    = (const float*)d_in[28];
    const float* ffn_b2    = (const float*)d_in[29];
    float* outp = (float*)d_out;

    // ---- workspace layout ----
    float* ws     = (float*)d_ws;
    float* bc     = ws;                     // 393216  (12288 x 32: B|C)
    float* proj   = bc     + 393216;        // 2097152
    float* proj2  = proj   + 2097152;       // 2097152 (split-K partial)
    float* t1     = proj2  + 2097152;       // 2097152
    float* tbuf   = t1     + 2097152;       // 2097152
    float* part_h = tbuf   + 2097152;       // 4194304
    float* part_s = part_h + 4194304;       // 262144
    unsigned short* ub      = (unsigned short*)(part_s + 262144);
    unsigned short* dltb    = ub;                   // 12582912 (bf16 delta; ffnout aliases)
    unsigned short* catb    = dltb    + 12582912;   // 6291456
    unsigned short* tgtb    = catb    + 6291456;    // 2097152
    unsigned short* xzb     = tgtb    + 2097152;    // 25165824 (also fbuf alias)
    unsigned short* xcb     = xzb     + 25165824;   // 12582912
    unsigned short* ygb     = xcb     + 12582912;   // 12582912
    unsigned short* tbbf    = ygb     + 12582912;   // 2097152
    unsigned short* s_in_wb = tbbf    + 2097152;    // 1048576  (6-weight block, contiguous)
    unsigned short* c_in_wb = s_in_wb + 1048576;    // 1048576
    unsigned short* s_out_wb= c_in_wb + 1048576;    // 524288
    unsigned short* c_out_wb= s_out_wb+ 524288;     // 524288
    unsigned short* w1b     = c_out_wb+ 524288;     // 1048576
    unsigned short* w2b     = w1b     + 1048576;    // 1048576
    unsigned short* xprojb_s= w2b     + 1048576;    // 131072 (128 x 1024, padded)
    unsigned short* xprojb_c= xprojb_s+ 131072;     // 131072
    unsigned short* dtwb_s  = xprojb_c+ 131072;     // 65536  (1024 x 64, padded)
    unsigned short* dtwb_c  = dtwb_s  + 65536;      // 65536
    unsigned short* dtb     = dtwb_c  + 65536;      // 786432 (12288 x 64: dt | zeros)
    unsigned short* fbuf    = xzb;                  // FFN hidden alias
    float* ffnout  = (float*)dltb;                  // alias (dltb dead after cross scan)
    float* ffnout2 = ffnout + 2097152;              // split-K partial (fits in dltb region)

    // ---- converts & weight fills ----
    f2b_kernel<<<(2097152/4 + 255)/256, 256, 0, stream>>>(tgt, tgtb, 2097152/4);
    mem2catb_kernel<<<(BB*TTM*DM/4 + 255)/256, 256, 0, stream>>>(memory, catb);
    {
        W6 w; w.p[0]=s_in_w; w.p[1]=c_in_w; w.p[2]=s_out_w; w.p[3]=c_out_w; w.p[4]=ffn_w1; w.p[5]=ffn_w2;
        wconv_kernel<<<(1310720 + 255)/256, 256, 0, stream>>>(w, s_in_wb);
    }
    xprojb_fill<<<131072/256, 256, 0, stream>>>(s_xproj_w, xprojb_s);
    xprojb_fill<<<131072/256, 256, 0, stream>>>(c_xproj_w, xprojb_c);
    dtwb_fill<<<65536/256, 256, 0, stream>>>(s_dt_w, dtwb_s);
    dtwb_fill<<<65536/256, 256, 0, stream>>>(c_dt_w, dtwb_c);

    // ---- self mamba (L=512, M=4096) ----
    mgemm_kernel<<<dim3(2048/128, 4096/128), 256, 0, stream>>>(
        tgtb, 4096, 0, 0, s_in_wb, nullptr, nullptr, xzb, nullptr, nullptr, 2048, 512, ACT_NONE);
    conv_silu_kernel<<<(BB*SS*DI/8 + 255)/256, 256, 0, stream>>>(xzb, s_conv_w, s_conv_b, xcb, SS, BB*SS*DI/8);
    // delta path stage 1: x_dbl = xc @ xproj^T (N=128 padded) -> dt bf16 + bc fp32
    mgemm_kernel<<<dim3(1, 4096/128), 256, 0, stream>>>(
        xcb, 4096, 0, 0, xprojb_s, nullptr, nullptr, dtb, bc, nullptr, 128, 1024, ACT_XDBL);
    // delta path stage 2: delta = softplus(dt @ dt_w^T + dt_b), K=64 (one k-iter)
    mgemm_kernel<<<dim3(1024/128, 4096/128), 256, 0, stream>>>(
        dtb, 4096, 0, 0, dtwb_s, s_dt_b, nullptr, dltb, nullptr, nullptr, 1024, 64, ACT_DELTA);
    run_scan(dltb, xcb, bc, xzb, s_A_log, s_D_vec, part_h, part_s, ygb, SS, stream);
    mgemm_kernel<<<dim3(512/128, 4096/128, 2), 256, 0, stream>>>(
        ygb, 4096, 0, 0, s_out_wb, nullptr, proj, nullptr, nullptr, proj2, 512, 1024, ACT_NONE);
    addln_kernel<<<4096, 128, 0, stream>>>(
        tgt, 4096, 0, 0, DM, proj, proj2, ln1_g, ln1_b,
        t1, 4096, 0, 0, DM, catb, 512, 1536, 1024, DM);

    // ---- cross mamba (L=1536, M=12288) ----
    mgemm_kernel<<<dim3(2048/128, 12288/128), 256, 0, stream>>>(
        catb, 12288, 0, 0, c_in_wb, nullptr, nullptr, xzb, nullptr, nullptr, 2048, 512, ACT_NONE);
    conv_silu_kernel<<<(BB*LCAT*DI/8 + 255)/256, 256, 0, stream>>>(xzb, c_conv_w, c_conv_b, xcb, LCAT, BB*LCAT*DI/8);
    mgemm_kernel<<<dim3(1, 12288/128), 256, 0, stream>>>(
        xcb, 12288, 0, 0, xprojb_c, nullptr, nullptr, dtb, bc, nullptr, 128, 1024, ACT_XDBL);
    mgemm_kernel<<<dim3(1024/128, 12288/128), 256, 0, stream>>>(
        dtb, 12288, 0, 0, dtwb_c, c_dt_b, nullptr, dltb, nullptr, nullptr, 1024, 64, ACT_DELTA);
    run_scan(dltb, xcb, bc, xzb, c_A_log, c_D_vec, part_h, part_s, ygb, LCAT, stream);
    mgemm_kernel<<<dim3(512/128, 4096/128, 2), 256, 0, stream>>>(
        ygb, 512, 1536, 1024, c_out_wb, nullptr, proj, nullptr, nullptr, proj2, 512, 1024, ACT_NONE);
    addln_kernel<<<4096, 128, 0, stream>>>(
        t1, 4096, 0, 0, DM, proj, proj2, ln2_g, ln2_b,
        tbuf, 4096, 0, 0, DM, tbbf, 4096, 0, 0, DM);

    // ---- FFN ----
    mgemm_kernel<<<dim3(2048/128, 4096/128), 256, 0, stream>>>(
        tbbf, 4096, 0, 0, w1b, ffn_b1, nullptr, fbuf, nullptr, nullptr, 2048, 512, ACT_RELU);
    mgemm_kernel<<<dim3(512/128, 4096/128, 2), 256, 0, stream>>>(
        fbuf, 4096, 0, 0, w2b, ffn_b2, ffnout, nullptr, nullptr, ffnout2, 512, 2048, ACT_NONE);
    addln_kernel<<<4096, 128, 0, stream>>>(
        tbuf, 4096, 0, 0, DM, ffnout, ffnout2, ln3_g, ln3_b,
        outp, 4096, 0, 0, DM, nullptr, 0, 0, 0, 0);
}